// Round 1
// baseline (201.196 us; speedup 1.0000x reference)
//
#include <hip/hip_runtime.h>
#include <cstdint>

// ViT patch embedding: out[n,197,768] = concat(cls, patchify(images) @ W^T + b)
// images: [128,3,224,224] fp32. Patch grid 14x14, patch 16x16, K = 3*16*16 = 768.
// GEMM: M = n*196 (=25088), N = 768, K = 768, bf16 MFMA 16x16x32.

#define PGRID 14
#define PSZ   16
#define CHN   3
#define IMGW  224
#define KDIM  768
#define NDIM  768
#define NPATCH 196

typedef short bf16x8 __attribute__((ext_vector_type(8)));
typedef float f32x4  __attribute__((ext_vector_type(4)));

__device__ __forceinline__ short bf16rne(float f) {
    uint32_t u = __builtin_bit_cast(uint32_t, f);
    u += 0x7FFFu + ((u >> 16) & 1u);
    return (short)(u >> 16);
}

// LDS row stride in shorts: 32 data + 8 pad = 40 (80 B rows -> 16B aligned, 2-way bank alias = free)
#define LDSTR 40

__global__ __launch_bounds__(256) void vit_gemm(
    const float* __restrict__ img, const float* __restrict__ Wl,
    const float* __restrict__ bias, float* __restrict__ out, int n_img)
{
    const int M = n_img * NPATCH;
    __shared__ short As[128 * LDSTR];
    __shared__ short Bs[128 * LDSTR];

    const int tid = threadIdx.x;
    const int m0 = blockIdx.y * 128;
    const int n0 = blockIdx.x * 128;

    // ---- staging thread coords: 256 threads cover 128 rows x 8 float4-cols (BK=32)
    const int col4  = tid & 7;     // float4 column (4 k-elements)
    const int rbase = tid >> 3;    // 0..31, rows rbase + 32*rr

    // Per-row patchify base offsets (row -> image location), hoisted out of k-loop
    long arow[4];
    for (int rr = 0; rr < 4; ++rr) {
        int m = m0 + rbase + rr * 32;
        int mm = (m < M) ? m : (M - 1);
        int im = mm / NPATCH;
        int p  = mm % NPATCH;
        int Pi = p / PGRID;
        int Pj = p % PGRID;
        arow[rr] = ((long)(im * CHN) * IMGW + Pi * PSZ) * IMGW + Pj * PSZ;
    }

    // ---- compute coords
    const int lane = tid & 63;
    const int wave = tid >> 6;          // 4 waves: 2x2 of 64x64
    const int wm = (wave & 1) * 64;
    const int wn = (wave >> 1) * 64;
    const int wq = lane >> 4;           // quad 0..3
    const int lr = lane & 15;

    f32x4 acc[4][4] = {};

    for (int k0 = 0; k0 < KDIM; k0 += 32) {
        // A staging (patchify + cvt bf16)
        {
            int k  = k0 + col4 * 4;
            int c  = k >> 8;
            int ph = (k >> 4) & 15;
            int pw = k & 15;
            long koff = (long)(c * IMGW + ph) * IMGW + pw;
            #pragma unroll
            for (int rr = 0; rr < 4; ++rr) {
                const float4 v = *(const float4*)(img + arow[rr] + koff);
                int row = rbase + rr * 32;
                short4 s;
                s.x = bf16rne(v.x); s.y = bf16rne(v.y);
                s.z = bf16rne(v.z); s.w = bf16rne(v.w);
                *(short4*)(&As[row * LDSTR + col4 * 4]) = s;
            }
        }
        // B staging: Bs[n][k] = W[n0+n][k0+k]
        {
            int k = k0 + col4 * 4;
            #pragma unroll
            for (int rr = 0; rr < 4; ++rr) {
                int nrow = rbase + rr * 32;
                const float4 v = *(const float4*)(Wl + (long)(n0 + nrow) * KDIM + k);
                short4 s;
                s.x = bf16rne(v.x); s.y = bf16rne(v.y);
                s.z = bf16rne(v.z); s.w = bf16rne(v.w);
                *(short4*)(&Bs[nrow * LDSTR + col4 * 4]) = s;
            }
        }
        __syncthreads();

        bf16x8 a[4], b[4];
        #pragma unroll
        for (int i = 0; i < 4; ++i)
            a[i] = *(const bf16x8*)(&As[(wm + i * 16 + lr) * LDSTR + wq * 8]);
        #pragma unroll
        for (int i = 0; i < 4; ++i)
            b[i] = *(const bf16x8*)(&Bs[(wn + i * 16 + lr) * LDSTR + wq * 8]);
        #pragma unroll
        for (int i = 0; i < 4; ++i)
            #pragma unroll
            for (int j = 0; j < 4; ++j)
                acc[i][j] = __builtin_amdgcn_mfma_f32_16x16x32_bf16(a[i], b[j], acc[i][j], 0, 0, 0);
        __syncthreads();
    }

    // ---- epilogue: C[m][n] + bias -> out[img, 1+p, n]
    float bv[4];
    #pragma unroll
    for (int j = 0; j < 4; ++j) bv[j] = bias[n0 + wn + j * 16 + lr];

    #pragma unroll
    for (int i = 0; i < 4; ++i) {
        #pragma unroll
        for (int r = 0; r < 4; ++r) {
            int gm = m0 + wm + i * 16 + wq * 4 + r;
            if (gm < M) {
                int im = gm / NPATCH;
                int p  = gm % NPATCH;
                long orow = ((long)im * 197 + 1 + p) * (long)NDIM;
                #pragma unroll
                for (int j = 0; j < 4; ++j) {
                    out[orow + n0 + wn + j * 16 + lr] = acc[i][j][r] + bv[j];
                }
            }
        }
    }
}

__global__ __launch_bounds__(256) void cls_fill(
    const float* __restrict__ cls, float* __restrict__ out, int n_img)
{
    int i = blockIdx.x * 256 + threadIdx.x;
    if (i < n_img * NDIM) {
        int im = i / NDIM;
        int n  = i - im * NDIM;
        out[(long)im * 197 * NDIM + n] = cls[n];
    }
}

extern "C" void kernel_launch(void* const* d_in, const int* in_sizes, int n_in,
                              void* d_out, int out_size, void* d_ws, size_t ws_size,
                              hipStream_t stream) {
    const float* img  = (const float*)d_in[0];
    const float* Wl   = (const float*)d_in[1];
    const float* bias = (const float*)d_in[2];
    const float* cls  = (const float*)d_in[3];
    float* out = (float*)d_out;

    int n_img = in_sizes[0] / (CHN * IMGW * IMGW);
    int M = n_img * NPATCH;

    dim3 grid(NDIM / 128, (M + 127) / 128);
    vit_gemm<<<grid, 256, 0, stream>>>(img, Wl, bias, out, n_img);

    int cls_elems = n_img * NDIM;
    cls_fill<<<(cls_elems + 255) / 256, 256, 0, stream>>>(cls, out, n_img);
}

// Round 2
// 193.914 us; speedup vs baseline: 1.0375x; 1.0375x over previous
//
#include <hip/hip_runtime.h>
#include <cstdint>

// ViT patch embedding, two-stage:
//   prep_patch: images fp32 [n,3,224,224] -> patchified bf16 A[M=196n][768] in ws
//   prep_small: W fp32 -> bf16 Wb[768][768] in ws; cls rows -> out
//   vit_gemm2:  m97-style bf16 GEMM (global_load_lds w16, XOR-swizzled LDS, BK=64)
// Fallback single-kernel path if ws too small.

#define PGRID 14
#define PSZ   16
#define CHN   3
#define IMGW  224
#define KDIM  768
#define NDIM  768
#define NPATCH 196

typedef short bf16x8 __attribute__((ext_vector_type(8)));
typedef short short8v __attribute__((ext_vector_type(8)));
typedef float f32x4  __attribute__((ext_vector_type(4)));

__device__ __forceinline__ short bf16rne(float f) {
    uint32_t u = __builtin_bit_cast(uint32_t, f);
    u += 0x7FFFu + ((u >> 16) & 1u);
    return (short)(u >> 16);
}

__device__ __forceinline__ short8v cvt8(float4 v0, float4 v1) {
    short8v s;
    s[0] = bf16rne(v0.x); s[1] = bf16rne(v0.y); s[2] = bf16rne(v0.z); s[3] = bf16rne(v0.w);
    s[4] = bf16rne(v1.x); s[5] = bf16rne(v1.y); s[6] = bf16rne(v1.z); s[7] = bf16rne(v1.w);
    return s;
}

__device__ __forceinline__ void gload_lds16(const void* g, void* l) {
    __builtin_amdgcn_global_load_lds(
        (const __attribute__((address_space(1))) unsigned int*)g,
        (__attribute__((address_space(3))) unsigned int*)l, 16, 0, 0);
}

// ---------------- prep: patchify + fp32->bf16 ----------------
__global__ __launch_bounds__(256) void prep_patch(
    const float* __restrict__ img, short* __restrict__ A, int M)
{
    int t = blockIdx.x * 256 + threadIdx.x;
    if (t >= M * 96) return;
    int m  = t / 96;
    int k8 = t - m * 96;
    int k  = k8 * 8;
    int c  = k >> 8;
    int ph = (k >> 4) & 15;
    int pw = k & 15;          // 0 or 8
    int im = m / NPATCH;
    int p  = m - im * NPATCH;
    int Pi = p / PGRID;
    int Pj = p - Pi * PGRID;
    const float* src = img + (((long)(im * CHN + c) * IMGW + Pi * PSZ + ph) * IMGW + Pj * PSZ + pw);
    float4 v0 = *(const float4*)src;
    float4 v1 = *(const float4*)(src + 4);
    *(short8v*)(A + (long)m * KDIM + k) = cvt8(v0, v1);
}

// ---------------- prep: W convert + cls fill ----------------
__global__ __launch_bounds__(256) void prep_small(
    const float* __restrict__ Wl, const float* __restrict__ cls,
    short* __restrict__ Wb, float* __restrict__ out, int n_img)
{
    int t = blockIdx.x * 256 + threadIdx.x;
    const int WCH = KDIM * NDIM / 8;   // 73728
    if (t < WCH) {
        float4 v0 = *(const float4*)(Wl + (long)t * 8);
        float4 v1 = *(const float4*)(Wl + (long)t * 8 + 4);
        *(short8v*)(Wb + (long)t * 8) = cvt8(v0, v1);
    } else {
        int u = t - WCH;
        if (u < n_img * 96) {
            int im = u / 96;
            int k8 = u - im * 96;
            float4 v0 = *(const float4*)(cls + k8 * 8);
            float4 v1 = *(const float4*)(cls + k8 * 8 + 4);
            float* dst = out + (long)im * 197 * NDIM + k8 * 8;
            *(float4*)dst = v0;
            *(float4*)(dst + 4) = v1;
        }
    }
}

// ---------------- main GEMM: bf16 A[M][768] @ Wb[768][768]^T + bias ----------------
__global__ __launch_bounds__(256) void vit_gemm2(
    const short* __restrict__ A, const short* __restrict__ B,
    const float* __restrict__ bias, float* __restrict__ out, int M)
{
    __shared__ short As[128 * 64];   // 16 KB, XOR-swizzled: (row, k16) at row*64 + ((k16^(row&7))*8)
    __shared__ short Bs[128 * 64];

    const int tid = threadIdx.x;
    const int m0 = blockIdx.y * 128;
    const int n0 = blockIdx.x * 128;
    const int wave = tid >> 6;
    const int lane = tid & 63;

    // staging coords: block b = j*256 + tid; physical LDS slot = b; logical row = b>>3,
    // logical k16 chunk = (b&7) ^ (row&7)  -> swizzle applied via global gather address
    const int srow = tid >> 3;                       // + 32*j per round
    const int sk   = (tid & 7) ^ (srow & 7);
    const long abase = (long)(m0 + srow) * KDIM + sk * 8;
    const long bbase = (long)(n0 + srow) * KDIM + sk * 8;
    char* AsB = (char*)As;
    char* BsB = (char*)Bs;
    const int ldsw = wave * 1024;                    // per-wave window within a 4 KB round

    // compute coords
    const int wm = (wave & 1) * 64;
    const int wn = (wave >> 1) * 64;
    const int wq = lane >> 4;
    const int lr = lane & 15;
    const int blk0 = ((wq)     ^ (lr & 7)) * 8;      // swizzled k-chunk offsets (shorts)
    const int blk1 = ((wq + 4) ^ (lr & 7)) * 8;

    f32x4 acc[4][4] = {};

    for (int kk = 0; kk < KDIM; kk += 64) {
        #pragma unroll
        for (int j = 0; j < 4; ++j) {
            gload_lds16(A + abase + (long)j * 32 * KDIM + kk, AsB + j * 4096 + ldsw);
            gload_lds16(B + bbase + (long)j * 32 * KDIM + kk, BsB + j * 4096 + ldsw);
        }
        __syncthreads();

        #pragma unroll
        for (int ks = 0; ks < 2; ++ks) {
            const int blk = ks ? blk1 : blk0;
            bf16x8 a[4], b[4];
            #pragma unroll
            for (int i = 0; i < 4; ++i)
                a[i] = *(const bf16x8*)(&As[(wm + i * 16 + lr) * 64 + blk]);
            #pragma unroll
            for (int i = 0; i < 4; ++i)
                b[i] = *(const bf16x8*)(&Bs[(wn + i * 16 + lr) * 64 + blk]);
            #pragma unroll
            for (int i = 0; i < 4; ++i)
                #pragma unroll
                for (int j = 0; j < 4; ++j)
                    acc[i][j] = __builtin_amdgcn_mfma_f32_16x16x32_bf16(a[i], b[j], acc[i][j], 0, 0, 0);
        }
        __syncthreads();
    }

    float bv[4];
    #pragma unroll
    for (int j = 0; j < 4; ++j) bv[j] = bias[n0 + wn + j * 16 + lr];

    #pragma unroll
    for (int i = 0; i < 4; ++i) {
        #pragma unroll
        for (int r = 0; r < 4; ++r) {
            int gm = m0 + wm + i * 16 + wq * 4 + r;
            if (gm < M) {
                int im = gm / NPATCH;
                int p  = gm - im * NPATCH;
                long orow = ((long)im * 197 + 1 + p) * (long)NDIM;
                #pragma unroll
                for (int j = 0; j < 4; ++j)
                    out[orow + n0 + wn + j * 16 + lr] = acc[i][j][r] + bv[j];
            }
        }
    }
}

// ---------------- fallback (round-1 fused kernel) ----------------
#define LDSTR 40
__global__ __launch_bounds__(256) void vit_gemm_fb(
    const float* __restrict__ img, const float* __restrict__ Wl,
    const float* __restrict__ bias, float* __restrict__ out, int n_img)
{
    const int M = n_img * NPATCH;
    __shared__ short As[128 * LDSTR];
    __shared__ short Bs[128 * LDSTR];
    const int tid = threadIdx.x;
    const int m0 = blockIdx.y * 128;
    const int n0 = blockIdx.x * 128;
    const int col4  = tid & 7;
    const int rbase = tid >> 3;
    long arow[4];
    for (int rr = 0; rr < 4; ++rr) {
        int m = m0 + rbase + rr * 32;
        int mm = (m < M) ? m : (M - 1);
        int im = mm / NPATCH;
        int p  = mm % NPATCH;
        int Pi = p / PGRID;
        int Pj = p % PGRID;
        arow[rr] = ((long)(im * CHN) * IMGW + Pi * PSZ) * IMGW + Pj * PSZ;
    }
    const int lane = tid & 63;
    const int wave = tid >> 6;
    const int wm = (wave & 1) * 64;
    const int wn = (wave >> 1) * 64;
    const int wq = lane >> 4;
    const int lr = lane & 15;
    f32x4 acc[4][4] = {};
    for (int k0 = 0; k0 < KDIM; k0 += 32) {
        {
            int k  = k0 + col4 * 4;
            int c  = k >> 8;
            int ph = (k >> 4) & 15;
            int pw = k & 15;
            long koff = (long)(c * IMGW + ph) * IMGW + pw;
            #pragma unroll
            for (int rr = 0; rr < 4; ++rr) {
                const float4 v = *(const float4*)(img + arow[rr] + koff);
                int row = rbase + rr * 32;
                short4 s;
                s.x = bf16rne(v.x); s.y = bf16rne(v.y);
                s.z = bf16rne(v.z); s.w = bf16rne(v.w);
                *(short4*)(&As[row * LDSTR + col4 * 4]) = s;
            }
        }
        {
            int k = k0 + col4 * 4;
            #pragma unroll
            for (int rr = 0; rr < 4; ++rr) {
                int nrow = rbase + rr * 32;
                const float4 v = *(const float4*)(Wl + (long)(n0 + nrow) * KDIM + k);
                short4 s;
                s.x = bf16rne(v.x); s.y = bf16rne(v.y);
                s.z = bf16rne(v.z); s.w = bf16rne(v.w);
                *(short4*)(&Bs[nrow * LDSTR + col4 * 4]) = s;
            }
        }
        __syncthreads();
        bf16x8 a[4], b[4];
        #pragma unroll
        for (int i = 0; i < 4; ++i)
            a[i] = *(const bf16x8*)(&As[(wm + i * 16 + lr) * LDSTR + wq * 8]);
        #pragma unroll
        for (int i = 0; i < 4; ++i)
            b[i] = *(const bf16x8*)(&Bs[(wn + i * 16 + lr) * LDSTR + wq * 8]);
        #pragma unroll
        for (int i = 0; i < 4; ++i)
            #pragma unroll
            for (int j = 0; j < 4; ++j)
                acc[i][j] = __builtin_amdgcn_mfma_f32_16x16x32_bf16(a[i], b[j], acc[i][j], 0, 0, 0);
        __syncthreads();
    }
    float bv[4];
    #pragma unroll
    for (int j = 0; j < 4; ++j) bv[j] = bias[n0 + wn + j * 16 + lr];
    #pragma unroll
    for (int i = 0; i < 4; ++i) {
        #pragma unroll
        for (int r = 0; r < 4; ++r) {
            int gm = m0 + wm + i * 16 + wq * 4 + r;
            if (gm < M) {
                int im = gm / NPATCH;
                int p  = gm % NPATCH;
                long orow = ((long)im * 197 + 1 + p) * (long)NDIM;
                #pragma unroll
                for (int j = 0; j < 4; ++j)
                    out[orow + n0 + wn + j * 16 + lr] = acc[i][j][r] + bv[j];
            }
        }
    }
}

__global__ __launch_bounds__(256) void cls_fill(
    const float* __restrict__ cls, float* __restrict__ out, int n_img)
{
    int i = blockIdx.x * 256 + threadIdx.x;
    if (i < n_img * NDIM) {
        int im = i / NDIM;
        int n  = i - im * NDIM;
        out[(long)im * 197 * NDIM + n] = cls[n];
    }
}

extern "C" void kernel_launch(void* const* d_in, const int* in_sizes, int n_in,
                              void* d_out, int out_size, void* d_ws, size_t ws_size,
                              hipStream_t stream) {
    const float* img  = (const float*)d_in[0];
    const float* Wl   = (const float*)d_in[1];
    const float* bias = (const float*)d_in[2];
    const float* cls  = (const float*)d_in[3];
    float* out = (float*)d_out;

    int n_img = in_sizes[0] / (CHN * IMGW * IMGW);
    int M = n_img * NPATCH;
    int mblocks = (M + 127) / 128;
    long Mpad = (long)mblocks * 128;

    size_t need = (size_t)(Mpad * KDIM + (long)KDIM * NDIM) * sizeof(short);
    if (ws_size >= need) {
        short* A_ws = (short*)d_ws;
        short* Wb   = A_ws + Mpad * KDIM;

        prep_patch<<<(M * 96 + 255) / 256, 256, 0, stream>>>(img, A_ws, M);
        int small_total = KDIM * NDIM / 8 + n_img * 96;
        prep_small<<<(small_total + 255) / 256, 256, 0, stream>>>(Wl, cls, Wb, out, n_img);

        dim3 grid(NDIM / 128, mblocks);
        vit_gemm2<<<grid, 256, 0, stream>>>(A_ws, Wb, bias, out, M);
    } else {
        dim3 grid(NDIM / 128, mblocks);
        vit_gemm_fb<<<grid, 256, 0, stream>>>(img, Wl, bias, out, n_img);
        int cls_elems = n_img * NDIM;
        cls_fill<<<(cls_elems + 255) / 256, 256, 0, stream>>>(cls, out, n_img);
    }
}

// Round 3
// 181.433 us; speedup vs baseline: 1.1089x; 1.0688x over previous
//
#include <hip/hip_runtime.h>
#include <cstdint>

// ViT patch embedding, two-stage:
//   prep_patch: images fp32 [n,3,224,224] -> patchified bf16 A[M=196n][768] in ws
//   prep_small: W fp32 -> bf16 Wb[768][768] in ws; cls rows -> out
//   vit_gemm3:  bf16 GEMM, register-pipelined staging (global->VGPR->ds_write),
//               single LDS buffer, XOR-swizzled (0 bank conflicts, verified R2),
//               XCD-swizzled grid so the 6 n-blocks sharing an A-tile co-locate.
// Register staging (not global_load_lds) so __syncthreads needs no vmcnt(0)
// drain — the R2 kernel was barrier-latency-bound on exactly that drain.

#define PGRID 14
#define PSZ   16
#define CHN   3
#define IMGW  224
#define KDIM  768
#define NDIM  768
#define NPATCH 196

typedef short bf16x8 __attribute__((ext_vector_type(8)));
typedef short short8v __attribute__((ext_vector_type(8)));
typedef float f32x4  __attribute__((ext_vector_type(4)));

__device__ __forceinline__ short bf16rne(float f) {
    uint32_t u = __builtin_bit_cast(uint32_t, f);
    u += 0x7FFFu + ((u >> 16) & 1u);
    return (short)(u >> 16);
}

__device__ __forceinline__ short8v cvt8(float4 v0, float4 v1) {
    short8v s;
    s[0] = bf16rne(v0.x); s[1] = bf16rne(v0.y); s[2] = bf16rne(v0.z); s[3] = bf16rne(v0.w);
    s[4] = bf16rne(v1.x); s[5] = bf16rne(v1.y); s[6] = bf16rne(v1.z); s[7] = bf16rne(v1.w);
    return s;
}

// ---------------- prep: patchify + fp32->bf16 ----------------
__global__ __launch_bounds__(256) void prep_patch(
    const float* __restrict__ img, short* __restrict__ A, int M)
{
    int t = blockIdx.x * 256 + threadIdx.x;
    if (t >= M * 96) return;
    int m  = t / 96;
    int k8 = t - m * 96;
    int k  = k8 * 8;
    int c  = k >> 8;
    int ph = (k >> 4) & 15;
    int pw = k & 15;          // 0 or 8
    int im = m / NPATCH;
    int p  = m - im * NPATCH;
    int Pi = p / PGRID;
    int Pj = p - Pi * PGRID;
    const float* src = img + (((long)(im * CHN + c) * IMGW + Pi * PSZ + ph) * IMGW + Pj * PSZ + pw);
    float4 v0 = *(const float4*)src;
    float4 v1 = *(const float4*)(src + 4);
    *(short8v*)(A + (long)m * KDIM + k) = cvt8(v0, v1);
}

// ---------------- prep: W convert + cls fill ----------------
__global__ __launch_bounds__(256) void prep_small(
    const float* __restrict__ Wl, const float* __restrict__ cls,
    short* __restrict__ Wb, float* __restrict__ out, int n_img)
{
    int t = blockIdx.x * 256 + threadIdx.x;
    const int WCH = KDIM * NDIM / 8;   // 73728
    if (t < WCH) {
        float4 v0 = *(const float4*)(Wl + (long)t * 8);
        float4 v1 = *(const float4*)(Wl + (long)t * 8 + 4);
        *(short8v*)(Wb + (long)t * 8) = cvt8(v0, v1);
    } else {
        int u = t - WCH;
        if (u < n_img * 96) {
            int im = u / 96;
            int k8 = u - im * 96;
            float4 v0 = *(const float4*)(cls + k8 * 8);
            float4 v1 = *(const float4*)(cls + k8 * 8 + 4);
            float* dst = out + (long)im * 197 * NDIM + k8 * 8;
            *(float4*)dst = v0;
            *(float4*)(dst + 4) = v1;
        }
    }
}

// ---------------- main GEMM: bf16 A[M][768] @ Wb[768][768]^T + bias ----------------
__global__ __launch_bounds__(256) void vit_gemm3(
    const short* __restrict__ A, const short* __restrict__ B,
    const float* __restrict__ bias, float* __restrict__ out,
    int M, int mgroups)
{
    // ---- XCD-aware decode: 6 n-blocks of one m-group land on the same XCD
    // (bid % 8 is the empirical XCD round-robin; wrong mapping => neutral).
    {
    }
    const int bid = blockIdx.x;
    const int xcd = bid & 7;
    const int s   = bid >> 3;
    const int gq  = s / 6;
    const int j   = s - gq * 6;
    const int g   = gq * 8 + xcd;          // m-group
    if (g >= mgroups) return;
    const int m0 = g * 128;
    const int n0 = j * 128;

    __shared__ short As[128 * 64];   // 16 KB, XOR-swizzled: (row, k16) at row*64 + ((k16^(row&7))*8)
    __shared__ short Bs[128 * 64];

    const int tid = threadIdx.x;
    const int wave = tid >> 6;
    const int lane = tid & 63;

    // staging coords: slot b = j*256 + tid; phys LDS offset = b*8 shorts;
    // logical row = b>>3 = j*32 + (tid>>3); logical chunk = (tid&7) ^ (row&7)
    const int srow = tid >> 3;
    const int sk   = (tid & 7) ^ (srow & 7);
    const long abase = (long)(m0 + srow) * KDIM + sk * 8;
    const long bbase = (long)(n0 + srow) * KDIM + sk * 8;

    // compute coords
    const int wm = (wave & 1) * 64;
    const int wn = (wave >> 1) * 64;
    const int wq = lane >> 4;
    const int lr = lane & 15;
    const int blk0 = ((wq)     ^ (lr & 7)) * 8;
    const int blk1 = ((wq + 4) ^ (lr & 7)) * 8;

    f32x4 acc[4][4] = {};
    bf16x8 ra[4], rb[4];

    // prologue: load tile 0 into registers
    #pragma unroll
    for (int jj = 0; jj < 4; ++jj) {
        ra[jj] = *(const bf16x8*)(A + abase + (long)jj * 32 * KDIM);
        rb[jj] = *(const bf16x8*)(B + bbase + (long)jj * 32 * KDIM);
    }

    for (int kk = 0; kk < KDIM; kk += 64) {
        // spill current regs to LDS (conflict-free: consecutive tid -> consecutive 16B)
        #pragma unroll
        for (int jj = 0; jj < 4; ++jj) {
            *(bf16x8*)(&As[(jj * 256 + tid) * 8]) = ra[jj];
            *(bf16x8*)(&Bs[(jj * 256 + tid) * 8]) = rb[jj];
        }
        __syncthreads();   // lgkm only — no global_load_lds => no vmcnt(0) drain

        // issue next tile's global loads; latency hides behind MFMA phase
        if (kk + 64 < KDIM) {
            #pragma unroll
            for (int jj = 0; jj < 4; ++jj) {
                ra[jj] = *(const bf16x8*)(A + abase + (long)jj * 32 * KDIM + kk + 64);
                rb[jj] = *(const bf16x8*)(B + bbase + (long)jj * 32 * KDIM + kk + 64);
            }
        }

        #pragma unroll
        for (int ks = 0; ks < 2; ++ks) {
            const int blk = ks ? blk1 : blk0;
            bf16x8 a[4], b[4];
            #pragma unroll
            for (int i = 0; i < 4; ++i)
                a[i] = *(const bf16x8*)(&As[(wm + i * 16 + lr) * 64 + blk]);
            #pragma unroll
            for (int i = 0; i < 4; ++i)
                b[i] = *(const bf16x8*)(&Bs[(wn + i * 16 + lr) * 64 + blk]);
            #pragma unroll
            for (int i = 0; i < 4; ++i)
                #pragma unroll
                for (int jm = 0; jm < 4; ++jm)
                    acc[i][jm] = __builtin_amdgcn_mfma_f32_16x16x32_bf16(a[i], b[jm], acc[i][jm], 0, 0, 0);
        }
        __syncthreads();   // reads of this tile done before next ds_write
    }

    float bv[4];
    #pragma unroll
    for (int jm = 0; jm < 4; ++jm) bv[jm] = bias[n0 + wn + jm * 16 + lr];

    #pragma unroll
    for (int i = 0; i < 4; ++i) {
        #pragma unroll
        for (int r = 0; r < 4; ++r) {
            int gm = m0 + wm + i * 16 + wq * 4 + r;
            if (gm < M) {
                int im = gm / NPATCH;
                int p  = gm - im * NPATCH;
                long orow = ((long)im * 197 + 1 + p) * (long)NDIM;
                #pragma unroll
                for (int jm = 0; jm < 4; ++jm)
                    out[orow + n0 + wn + jm * 16 + lr] = acc[i][jm][r] + bv[jm];
            }
        }
    }
}

// ---------------- fallback (round-1 fused kernel) ----------------
#define LDSTR 40
__global__ __launch_bounds__(256) void vit_gemm_fb(
    const float* __restrict__ img, const float* __restrict__ Wl,
    const float* __restrict__ bias, float* __restrict__ out, int n_img)
{
    const int M = n_img * NPATCH;
    __shared__ short As[128 * LDSTR];
    __shared__ short Bs[128 * LDSTR];
    const int tid = threadIdx.x;
    const int m0 = blockIdx.y * 128;
    const int n0 = blockIdx.x * 128;
    const int col4  = tid & 7;
    const int rbase = tid >> 3;
    long arow[4];
    for (int rr = 0; rr < 4; ++rr) {
        int m = m0 + rbase + rr * 32;
        int mm = (m < M) ? m : (M - 1);
        int im = mm / NPATCH;
        int p  = mm % NPATCH;
        int Pi = p / PGRID;
        int Pj = p % PGRID;
        arow[rr] = ((long)(im * CHN) * IMGW + Pi * PSZ) * IMGW + Pj * PSZ;
    }
    const int lane = tid & 63;
    const int wave = tid >> 6;
    const int wm = (wave & 1) * 64;
    const int wn = (wave >> 1) * 64;
    const int wq = lane >> 4;
    const int lr = lane & 15;
    f32x4 acc[4][4] = {};
    for (int k0 = 0; k0 < KDIM; k0 += 32) {
        {
            int k  = k0 + col4 * 4;
            int c  = k >> 8;
            int ph = (k >> 4) & 15;
            int pw = k & 15;
            long koff = (long)(c * IMGW + ph) * IMGW + pw;
            #pragma unroll
            for (int rr = 0; rr < 4; ++rr) {
                const float4 v = *(const float4*)(img + arow[rr] + koff);
                int row = rbase + rr * 32;
                short4 s;
                s.x = bf16rne(v.x); s.y = bf16rne(v.y);
                s.z = bf16rne(v.z); s.w = bf16rne(v.w);
                *(short4*)(&As[row * LDSTR + col4 * 4]) = s;
            }
        }
        {
            int k = k0 + col4 * 4;
            #pragma unroll
            for (int rr = 0; rr < 4; ++rr) {
                int nrow = rbase + rr * 32;
                const float4 v = *(const float4*)(Wl + (long)(n0 + nrow) * KDIM + k);
                short4 s;
                s.x = bf16rne(v.x); s.y = bf16rne(v.y);
                s.z = bf16rne(v.z); s.w = bf16rne(v.w);
                *(short4*)(&Bs[nrow * LDSTR + col4 * 4]) = s;
            }
        }
        __syncthreads();
        bf16x8 a[4], b[4];
        #pragma unroll
        for (int i = 0; i < 4; ++i)
            a[i] = *(const bf16x8*)(&As[(wm + i * 16 + lr) * LDSTR + wq * 8]);
        #pragma unroll
        for (int i = 0; i < 4; ++i)
            b[i] = *(const bf16x8*)(&Bs[(wn + i * 16 + lr) * LDSTR + wq * 8]);
        #pragma unroll
        for (int i = 0; i < 4; ++i)
            #pragma unroll
            for (int j = 0; j < 4; ++j)
                acc[i][j] = __builtin_amdgcn_mfma_f32_16x16x32_bf16(a[i], b[j], acc[i][j], 0, 0, 0);
        __syncthreads();
    }
    float bv[4];
    #pragma unroll
    for (int j = 0; j < 4; ++j) bv[j] = bias[n0 + wn + j * 16 + lr];
    #pragma unroll
    for (int i = 0; i < 4; ++i) {
        #pragma unroll
        for (int r = 0; r < 4; ++r) {
            int gm = m0 + wm + i * 16 + wq * 4 + r;
            if (gm < M) {
                int im = gm / NPATCH;
                int p  = gm % NPATCH;
                long orow = ((long)im * 197 + 1 + p) * (long)NDIM;
                #pragma unroll
                for (int j = 0; j < 4; ++j)
                    out[orow + n0 + wn + j * 16 + lr] = acc[i][j][r] + bv[j];
            }
        }
    }
}

__global__ __launch_bounds__(256) void cls_fill(
    const float* __restrict__ cls, float* __restrict__ out, int n_img)
{
    int i = blockIdx.x * 256 + threadIdx.x;
    if (i < n_img * NDIM) {
        int im = i / NDIM;
        int n  = i - im * NDIM;
        out[(long)im * 197 * NDIM + n] = cls[n];
    }
}

extern "C" void kernel_launch(void* const* d_in, const int* in_sizes, int n_in,
                              void* d_out, int out_size, void* d_ws, size_t ws_size,
                              hipStream_t stream) {
    const float* img  = (const float*)d_in[0];
    const float* Wl   = (const float*)d_in[1];
    const float* bias = (const float*)d_in[2];
    const float* cls  = (const float*)d_in[3];
    float* out = (float*)d_out;

    int n_img = in_sizes[0] / (CHN * IMGW * IMGW);
    int M = n_img * NPATCH;
    int mgroups = (M + 127) / 128;
    long Mpad = (long)mgroups * 128;

    size_t need = (size_t)(Mpad * KDIM + (long)KDIM * NDIM) * sizeof(short);
    if (ws_size >= need) {
        short* A_ws = (short*)d_ws;
        short* Wb   = A_ws + Mpad * KDIM;

        prep_patch<<<(M * 96 + 255) / 256, 256, 0, stream>>>(img, A_ws, M);
        int small_total = KDIM * NDIM / 8 + n_img * 96;
        prep_small<<<(small_total + 255) / 256, 256, 0, stream>>>(Wl, cls, Wb, out, n_img);

        // XCD-swizzled 1-D grid: pad m-groups to multiple of 8
        int gpad = (mgroups + 7) & ~7;
        int nblocks = gpad * 6;
        vit_gemm3<<<nblocks, 256, 0, stream>>>(A_ws, Wb, bias, out, M, mgroups);
    } else {
        dim3 grid(NDIM / 128, mgroups);
        vit_gemm_fb<<<grid, 256, 0, stream>>>(img, Wl, bias, out, n_img);
        int cls_elems = n_img * NDIM;
        cls_fill<<<(cls_elems + 255) / 256, 256, 0, stream>>>(cls, out, n_img);
    }
}